// Round 5
// baseline (445.230 us; speedup 1.0000x reference)
//
#include <hip/hip_runtime.h>

typedef __attribute__((ext_vector_type(4))) float f32x4;
typedef __attribute__((ext_vector_type(8))) short bf16x8;
typedef __attribute__((ext_vector_type(4))) unsigned int u32x4;

__device__ __forceinline__ unsigned short f2bf(float f) {
    union { float f; unsigned int u; } x; x.f = f;
    unsigned int u = x.u;
    return (unsigned short)((u + 0x7FFFu + ((u >> 16) & 1u)) >> 16);
}
__device__ __forceinline__ float bf2f(unsigned short b) {
    union { unsigned int u; float f; } x; x.u = ((unsigned int)b) << 16;
    return x.f;
}
__device__ __forceinline__ float u2f(unsigned int u) {
    union { unsigned int u; float f; } x; x.u = u; return x.f;
}

#define INV_SQRT_HD 0.17677669529663687f

// ---------------- transpose features [48][256][2816] -> bf16 [135168][256] ----------------
__global__ __launch_bounds__(256) void transpose_feat(const float* __restrict__ src,
                                                      unsigned short* __restrict__ dst) {
    __shared__ float tile[32][33];
    int img = blockIdx.z;
    int p0 = blockIdx.x * 32;   // pixel
    int d0 = blockIdx.y * 32;   // channel
    int tx = threadIdx.x & 31, ty = threadIdx.x >> 5;
    const float* s = src + (size_t)img * 256 * 2816;
    unsigned short* o = dst + (size_t)img * 2816 * 256;
#pragma unroll
    for (int i = 0; i < 4; i++) tile[ty + 8 * i][tx] = s[(size_t)(d0 + ty + 8 * i) * 2816 + p0 + tx];
    __syncthreads();
#pragma unroll
    for (int i = 0; i < 4; i++) o[(size_t)(p0 + ty + 8 * i) * 256 + d0 + tx] = f2bf(tile[tx][ty + 8 * i]);
}

// ---------------- camf: project points, sample features, q_off = query + camf ----------------
__global__ __launch_bounds__(256) void camf_kernel(
    const float* __restrict__ query, const float* __restrict__ points,
    const unsigned short* __restrict__ feat_t,
    const float* __restrict__ camM, const float* __restrict__ camb,
    float* __restrict__ q_off, float* __restrict__ pxy) {
    int cid = blockIdx.x;             // cam*7200 + b*900 + k
    int cam = cid / 7200;
    int bk  = cid % 7200;             // b*900 + k
    int b   = bk / 900;

    const float* p = points + (size_t)bk * 3;
    const float* M = camM + cam * 6;
    float s0 = M[0] * p[0] + M[1] * p[1] + M[2] * p[2] + camb[cam * 2 + 0];
    float s1 = M[3] * p[0] + M[4] * p[1] + M[5] * p[2] + camb[cam * 2 + 1];
    float sig0 = 1.f / (1.f + expf(-s0));
    float sig1 = 1.f / (1.f + expf(-s1));
    float px0 = sig0 * 32.f, px1 = sig1 * 88.f;
    float gx = 2.f * px0 / 32.f - 1.f, gy = 2.f * px1 / 88.f - 1.f;
    float ix = (gx + 1.f) * 0.5f * 87.f;
    float iy = (gy + 1.f) * 0.5f * 31.f;
    float x0 = floorf(ix), y0 = floorf(iy), x1 = x0 + 1.f, y1 = y0 + 1.f;
    float wx1 = ix - x0, wx0 = x1 - ix, wy1 = iy - y0, wy0 = y1 - iy;
    float m00 = (x0 >= 0.f && x0 <= 87.f && y0 >= 0.f && y0 <= 31.f) ? 1.f : 0.f;
    float m01 = (x1 >= 0.f && x1 <= 87.f && y0 >= 0.f && y0 <= 31.f) ? 1.f : 0.f;
    float m10 = (x0 >= 0.f && x0 <= 87.f && y1 >= 0.f && y1 <= 31.f) ? 1.f : 0.f;
    float m11 = (x1 >= 0.f && x1 <= 87.f && y1 >= 0.f && y1 <= 31.f) ? 1.f : 0.f;
    float w00 = wx0 * wy0 * m00, w01 = wx1 * wy0 * m01, w10 = wx0 * wy1 * m10, w11 = wx1 * wy1 * m11;
    int xi0 = (int)fminf(fmaxf(x0, 0.f), 87.f);
    int xi1 = (int)fminf(fmaxf(x1, 0.f), 87.f);
    int yi0 = (int)fminf(fmaxf(y0, 0.f), 31.f);
    int yi1 = (int)fminf(fmaxf(y1, 0.f), 31.f);

    size_t img = (size_t)(cam * 8 + b) * 2816;
    const unsigned short* f00 = feat_t + (img + yi0 * 88 + xi0) * 256;
    const unsigned short* f01 = feat_t + (img + yi0 * 88 + xi1) * 256;
    const unsigned short* f10 = feat_t + (img + yi1 * 88 + xi0) * 256;
    const unsigned short* f11 = feat_t + (img + yi1 * 88 + xi1) * 256;

    int c = threadIdx.x;
    float val = w00 * bf2f(f00[c]) + w01 * bf2f(f01[c]) + w10 * bf2f(f10[c]) + w11 * bf2f(f11[c]);
    q_off[(size_t)cid * 256 + c] = query[(size_t)bk * 256 + c] + val;
    if (c == 0) { pxy[cid * 2 + 0] = px0; pxy[cid * 2 + 1] = px1; }
}

// ---------------- prep: Mqk[n=h*256+c][kq] = sum_d W_q[h*32+d][kq]*W_k[h*32+d][c] * inv_sqrt ----------------
__global__ __launch_bounds__(256) void prep_mqk(const float* __restrict__ Wq, const float* __restrict__ bq,
                                                const float* __restrict__ Wk,
                                                float* __restrict__ Mqk, float* __restrict__ bqk) {
    int n = blockIdx.x;            // h*256 + c
    int h = n >> 8, c = n & 255;
    int t = threadIdx.x;           // kq
    float acc = 0.f, accb = 0.f;
#pragma unroll 8
    for (int d = 0; d < 32; ++d) {
        float wk = Wk[(h * 32 + d) * 256 + c];
        acc  += Wq[(size_t)(h * 32 + d) * 256 + t] * wk;
        accb += bq[h * 32 + d] * wk;
    }
    Mqk[(size_t)n * 256 + t] = acc * INV_SQRT_HD;
    if (t == 0) bqk[n] = accb * INV_SQRT_HD;
}

// ---------------- prep: vqk[h][kq] = sum_d W_q[h*32+d][kq]*b_k[h*32+d]; cqk[h] = b_q.b_k ----------------
__global__ __launch_bounds__(256) void prep_vqk(const float* __restrict__ Wq, const float* __restrict__ bq,
                                                const float* __restrict__ bk,
                                                float* __restrict__ vqk, float* __restrict__ cqk) {
    int h = blockIdx.x, t = threadIdx.x;
    float acc = 0.f, accc = 0.f;
#pragma unroll 8
    for (int d = 0; d < 32; ++d) {
        float b = bk[h * 32 + d];
        acc  += Wq[(size_t)(h * 32 + d) * 256 + t] * b;
        accc += bq[h * 32 + d] * b;
    }
    vqk[h * 256 + t] = acc * INV_SQRT_HD;
    if (t == 0) cqk[h] = accc * INV_SQRT_HD;
}

// ---------------- prep: WvTp packed-transposed bf16 W_v: [(c>>1)][dg][2] ----------------
__global__ __launch_bounds__(256) void prep_wvt(const float* __restrict__ Wv,
                                                unsigned short* __restrict__ WvTp) {
    int dg = blockIdx.x, c = threadIdx.x;
    WvTp[(size_t)(c >> 1) * 512 + dg * 2 + (c & 1)] = f2bf(Wv[(size_t)dg * 256 + c]);
}

// ---------------- split-bf16 MFMA GEMM (fp32 A/B in): C = A@B^T + bias ----------------
template <bool SPLIT, bool C_BF16>
__global__ __launch_bounds__(256) void gemm_bf16(
    const float* __restrict__ A, long long aBatch,
    const float* __restrict__ B, const float* __restrict__ bias,
    void* __restrict__ Cv, long long cBatch,
    int M, int N, int K, int lda) {
    __shared__ __align__(16) unsigned short Ah[64][40];
    __shared__ __align__(16) unsigned short Bh[64][40];
    __shared__ __align__(16) unsigned short Al[(SPLIT ? 64 : 1)][40];
    __shared__ __align__(16) unsigned short Bl[(SPLIT ? 64 : 1)][40];

    const int tid = threadIdx.x;
    const int m0 = blockIdx.x * 64, n0 = blockIdx.y * 64;
    const int batch = blockIdx.z;
    const float* Ab = A + (size_t)batch * aBatch;
    const int lane = tid & 63, wave = tid >> 6;
    const int wr = wave & 1, wc = wave >> 1;
    const int lrow = lane & 15, lk = lane >> 4;

    f32x4 acc[2][2] = {};

    for (int kt = 0; kt < K; kt += 32) {
        if (kt) __syncthreads();
        {
            int c4 = (tid & 7) * 4;
#pragma unroll
            for (int rep = 0; rep < 2; rep++) {
                int r = (tid >> 3) + rep * 32;
                int m = m0 + r; if (m >= M) m = M - 1;
                f32x4 v = *(const f32x4*)(Ab + (size_t)m * lda + kt + c4);
#pragma unroll
                for (int q = 0; q < 4; q++) {
                    unsigned short h = f2bf(v[q]);
                    Ah[r][c4 + q] = h;
                    if (SPLIT) Al[r][c4 + q] = f2bf(v[q] - bf2f(h));
                }
            }
        }
        {
            int c4 = (tid & 7) * 4;
#pragma unroll
            for (int rep = 0; rep < 2; rep++) {
                int r = (tid >> 3) + rep * 32;
                f32x4 v = *(const f32x4*)(B + (size_t)(n0 + r) * K + kt + c4);
#pragma unroll
                for (int q = 0; q < 4; q++) {
                    unsigned short h = f2bf(v[q]);
                    Bh[r][c4 + q] = h;
                    if (SPLIT) Bl[r][c4 + q] = f2bf(v[q] - bf2f(h));
                }
            }
        }
        __syncthreads();

        bf16x8 a_h[2], b_h[2], a_l[2], b_l[2];
#pragma unroll
        for (int i = 0; i < 2; i++) {
            a_h[i] = *(const bf16x8*)&Ah[wr * 32 + i * 16 + lrow][lk * 8];
            b_h[i] = *(const bf16x8*)&Bh[wc * 32 + i * 16 + lrow][lk * 8];
            if (SPLIT) {
                a_l[i] = *(const bf16x8*)&Al[wr * 32 + i * 16 + lrow][lk * 8];
                b_l[i] = *(const bf16x8*)&Bl[wc * 32 + i * 16 + lrow][lk * 8];
            }
        }
#pragma unroll
        for (int i = 0; i < 2; i++)
#pragma unroll
            for (int j = 0; j < 2; j++) {
                acc[i][j] = __builtin_amdgcn_mfma_f32_16x16x32_bf16(a_h[i], b_h[j], acc[i][j], 0, 0, 0);
                if (SPLIT) {
                    acc[i][j] = __builtin_amdgcn_mfma_f32_16x16x32_bf16(a_h[i], b_l[j], acc[i][j], 0, 0, 0);
                    acc[i][j] = __builtin_amdgcn_mfma_f32_16x16x32_bf16(a_l[i], b_h[j], acc[i][j], 0, 0, 0);
                }
            }
    }

#pragma unroll
    for (int i = 0; i < 2; i++)
#pragma unroll
        for (int j = 0; j < 2; j++) {
            int n = n0 + wc * 32 + j * 16 + lrow;
            float bs = bias[n];
#pragma unroll
            for (int jj = 0; jj < 4; jj++) {
                int m = m0 + wr * 32 + i * 16 + lk * 4 + jj;
                if (m < M) {
                    float val = acc[i][j][jj] + bs;
                    if (C_BF16)
                        ((unsigned short*)Cv)[(size_t)batch * cBatch + (size_t)m * N + n] = f2bf(val);
                    else
                        ((float*)Cv)[(size_t)batch * cBatch + (size_t)m * N + n] = val;
                }
            }
        }
}

// ---------------- fused deformable attention on RAW features ----------------
// block = (b,k), 512 threads, wave = head. Samples raw 256-ch features at the
// 24 offset points (shared by K and V paths via linearity), computes logits
// with folded qW, online-softmax-accumulates sbar, then projects with W_v.
__global__ __launch_bounds__(512) void attn_kernel(
    const float* __restrict__ qW,      // [7200][2048]  (pre-scaled by 1/sqrt(hd), b_q folded)
    const float* __restrict__ query,   // [7200][256]
    const float* __restrict__ vqk,     // [8][256]  (pre-scaled)
    const float* __restrict__ cqk,     // [8]       (pre-scaled)
    const unsigned short* __restrict__ WvTp,  // packed transposed W_v bf16
    const float* __restrict__ b_v,     // [256]
    const float* __restrict__ pxy, const float* __restrict__ offs,
    const unsigned short* __restrict__ feat_t,
    float* __restrict__ S) {
    int bk = blockIdx.x;            // b*900 + k
    int b = bk / 900, k = bk % 900;
    int h = threadIdx.x >> 6;       // wave = head
    int lane = threadIdx.x & 63;

    __shared__ __align__(16) float        ldsW[8][24][4];
    __shared__ __align__(16) unsigned int ldsI[8][24][4];
    __shared__ __align__(16) float        ldsS[8][256];
    __shared__ float ldsB[8];

    // qbk = (query . vqk_h + cqk_h)  [already scaled]
    float pq;
    {
        f32x4 qv = *(const f32x4*)(query + (size_t)bk * 256 + lane * 4);
        f32x4 vv = *(const f32x4*)(vqk + h * 256 + lane * 4);
        pq = qv[0] * vv[0] + qv[1] * vv[1] + qv[2] * vv[2] + qv[3] * vv[3];
        pq += __shfl_xor(pq, 1);
        pq += __shfl_xor(pq, 2);
        pq += __shfl_xor(pq, 4);
        pq += __shfl_xor(pq, 8);
        pq += __shfl_xor(pq, 16);
        pq += __shfl_xor(pq, 32);
    }
    const float qbk = pq + cqk[h];

    if (lane < 24) {
        int cam = lane >> 2, p = lane & 3;
        int cid = cam * 7200 + bk;
        float px0 = pxy[cid * 2 + 0], px1 = pxy[cid * 2 + 1];
        float o0 = offs[(size_t)cid * 64 + (h * 4 + p) * 2 + 0];
        float o1 = offs[(size_t)cid * 64 + (h * 4 + p) * 2 + 1];
        float pc0 = px0 + o0 * (1.f / 32.f);
        float pc1 = px1 + o1 * (1.f / 88.f);
        float gx = 2.f * (pc0 * (1.f / 32.f)) - 1.f;
        float gy = 2.f * (pc1 * (1.f / 88.f)) - 1.f;
        float ix = (gx + 1.f) * 0.5f * 87.f;
        float iy = (gy + 1.f) * 0.5f * 31.f;
        float x0 = floorf(ix), y0 = floorf(iy), x1 = x0 + 1.f, y1 = y0 + 1.f;
        float wx1 = ix - x0, wx0 = x1 - ix, wy1 = iy - y0, wy0 = y1 - iy;
        float m00 = (x0 >= 0.f && x0 <= 87.f && y0 >= 0.f && y0 <= 31.f) ? 1.f : 0.f;
        float m01 = (x1 >= 0.f && x1 <= 87.f && y0 >= 0.f && y0 <= 31.f) ? 1.f : 0.f;
        float m10 = (x0 >= 0.f && x0 <= 87.f && y1 >= 0.f && y1 <= 31.f) ? 1.f : 0.f;
        float m11 = (x1 >= 0.f && x1 <= 87.f && y1 >= 0.f && y1 <= 31.f) ? 1.f : 0.f;
        int xi0 = (int)fminf(fmaxf(x0, 0.f), 87.f);
        int xi1 = (int)fminf(fmaxf(x1, 0.f), 87.f);
        int yi0 = (int)fminf(fmaxf(y0, 0.f), 31.f);
        int yi1 = (int)fminf(fmaxf(y1, 0.f), 31.f);
        unsigned int img = (unsigned int)(cam * 8 + b) * 2816u;
        ldsW[h][lane][0] = wx0 * wy0 * m00;
        ldsW[h][lane][1] = wx1 * wy0 * m01;
        ldsW[h][lane][2] = wx0 * wy1 * m10;
        ldsW[h][lane][3] = wx1 * wy1 * m11;
        ldsI[h][lane][0] = (img + yi0 * 88 + xi0) * 512u;
        ldsI[h][lane][1] = (img + yi0 * 88 + xi1) * 512u;
        ldsI[h][lane][2] = (img + yi1 * 88 + xi0) * 512u;
        ldsI[h][lane][3] = (img + yi1 * 88 + xi1) * 512u;
    }
    __syncthreads();

    const int pt = lane >> 5;             // point parity
    const int c8 = (lane & 31) * 8;       // 8 channels per lane
    const char* fb = (const char*)feat_t;

    float qw[8];
    {
        f32x4 qa = *(const f32x4*)(qW + (size_t)bk * 2048 + h * 256 + c8);
        f32x4 qb = *(const f32x4*)(qW + (size_t)bk * 2048 + h * 256 + c8 + 4);
#pragma unroll
        for (int j = 0; j < 4; ++j) { qw[j] = qa[j]; qw[4 + j] = qb[j]; }
    }

    float mrun = -1e30f, den = 0.f, bsum = 0.f;
    float sb[8];
#pragma unroll
    for (int j = 0; j < 8; ++j) sb[j] = 0.f;

#pragma unroll
    for (int lp = 0; lp < 12; ++lp) {
        int l = lp * 2 + pt;
        f32x4 w = *(const f32x4*)ldsW[h][l];
        float Wl = w[0] + w[1] + w[2] + w[3];
        unsigned int cb = (unsigned int)(c8 * 2);
        u32x4 u0 = *(const u32x4*)(fb + ldsI[h][l][0] + cb);
        u32x4 u1 = *(const u32x4*)(fb + ldsI[h][l][1] + cb);
        u32x4 u2 = *(const u32x4*)(fb + ldsI[h][l][2] + cb);
        u32x4 u3 = *(const u32x4*)(fb + ldsI[h][l][3] + cb);
        float s[8];
#pragma unroll
        for (int i = 0; i < 4; ++i) {
            s[2 * i] = w[0] * u2f(u0[i] << 16) + w[1] * u2f(u1[i] << 16)
                     + w[2] * u2f(u2[i] << 16) + w[3] * u2f(u3[i] << 16);
            s[2 * i + 1] = w[0] * u2f(u0[i] & 0xFFFF0000u) + w[1] * u2f(u1[i] & 0xFFFF0000u)
                         + w[2] * u2f(u2[i] & 0xFFFF0000u) + w[3] * u2f(u3[i] & 0xFFFF0000u);
        }
        float t = 0.f;
#pragma unroll
        for (int j = 0; j < 8; ++j) t += qw[j] * s[j];
        t += __shfl_xor(t, 1);
        t += __shfl_xor(t, 2);
        t += __shfl_xor(t, 4);
        t += __shfl_xor(t, 8);
        t += __shfl_xor(t, 16);
        t += qbk * Wl;                         // logit (scaled)
        float t2 = __shfl_xor(t, 32);          // other parity's logit
        float mn = fmaxf(mrun, fmaxf(t, t2));
        float rs = __expf(mrun - mn);
        float e  = __expf(t - mn);
        den = den * rs + e;
        bsum = bsum * rs + e * Wl;
#pragma unroll
        for (int j = 0; j < 8; ++j) sb[j] = sb[j] * rs + e * s[j];
        mrun = mn;
    }

    den  += __shfl_xor(den, 32);
    bsum += __shfl_xor(bsum, 32);
#pragma unroll
    for (int j = 0; j < 8; ++j) sb[j] += __shfl_xor(sb[j], 32);
    float inv = 1.f / den;
    if (pt == 0) {
#pragma unroll
        for (int j = 0; j < 8; ++j) ldsS[h][c8 + j] = sb[j] * inv;
        if (lane == 0) ldsB[h] = bsum * inv;
    }
    __syncthreads();

    // value projection: weighted[d] = sum_c W_v[h*32+d][c] * sbarN[c] + b_v[h*32+d]*bsumN
    {
        int d = lane & 31, hf = lane >> 5;
        const unsigned int* wvp = (const unsigned int*)WvTp;
        float acc = 0.f;
#pragma unroll 16
        for (int i = 0; i < 64; ++i) {
            int cc = hf * 64 + i;                 // channel pair
            unsigned int u = wvp[cc * 256 + (h * 32 + d)];
            acc += u2f(u << 16) * ldsS[h][cc * 2]
                 + u2f(u & 0xFFFF0000u) * ldsS[h][cc * 2 + 1];
        }
        acc += __shfl_xor(acc, 32);
        if (lane < 32)
            S[(size_t)b * 230400 + (size_t)h * 28800 + k * 32 + d] =
                acc + b_v[h * 32 + d] * ldsB[h];
    }
}

extern "C" void kernel_launch(void* const* d_in, const int* in_sizes, int n_in,
                              void* d_out, int out_size, void* d_ws, size_t ws_size,
                              hipStream_t stream) {
    const float* query    = (const float*)d_in[0];
    const float* points   = (const float*)d_in[1];
    const float* features = (const float*)d_in[2];
    const float* camM     = (const float*)d_in[3];
    const float* camb     = (const float*)d_in[4];
    const float* W_off    = (const float*)d_in[5];
    const float* b_off    = (const float*)d_in[6];
    const float* W_q      = (const float*)d_in[7];
    const float* b_q      = (const float*)d_in[8];
    const float* W_k      = (const float*)d_in[9];
    const float* b_k      = (const float*)d_in[10];
    const float* W_v      = (const float*)d_in[11];
    const float* b_v      = (const float*)d_in[12];
    const float* W_o      = (const float*)d_in[13];
    const float* b_o      = (const float*)d_in[14];

    char* ws = (char*)d_ws;
    unsigned short* feat_t = (unsigned short*)ws; ws += 69206016;   // [135168][256] bf16
    float* q_off  = (float*)ws; ws += 44236800;                     // [43200][256]
    float* offs   = (float*)ws; ws += 11059200;                     // [43200][64]
    float* pxy    = (float*)ws; ws += 345600;                       // [43200][2]
    float* qW     = (float*)ws; ws += 58982400;                     // [7200][2048]
    float* S      = (float*)ws; ws += 7372800;                      // [8][230400] scrambled
    float* Mqk    = (float*)ws; ws += 2097152;                      // [2048][256]
    float* bqk    = (float*)ws; ws += 8192;                         // [2048]
    float* vqk    = (float*)ws; ws += 8192;                         // [8][256]
    float* cqk    = (float*)ws; ws += 64;                           // [8]
    unsigned short* WvTp = (unsigned short*)ws; ws += 131072;       // [128][256][2] bf16

    transpose_feat<<<dim3(88, 8, 48), 256, 0, stream>>>(features, feat_t);
    camf_kernel<<<43200, 256, 0, stream>>>(query, points, feat_t, camM, camb, q_off, pxy);
    prep_mqk<<<2048, 256, 0, stream>>>(W_q, b_q, W_k, Mqk, bqk);
    prep_vqk<<<8, 256, 0, stream>>>(W_q, b_q, b_k, vqk, cqk);
    prep_wvt<<<256, 256, 0, stream>>>(W_v, WvTp);
    // offsets = q_off @ W_off^T + b_off : [43200 x 64]
    gemm_bf16<true, false><<<dim3(675, 1, 1), 256, 0, stream>>>(
        q_off, 0, W_off, b_off, offs, 0, 43200, 64, 256, 256);
    // qW = query @ Mqk^T + bqk : [7200 x 2048]
    gemm_bf16<false, false><<<dim3(113, 32, 1), 256, 0, stream>>>(
        query, 0, Mqk, bqk, qW, 0, 7200, 2048, 256, 256);
    attn_kernel<<<7200, 512, 0, stream>>>(qW, query, vqk, cqk, WvTp, b_v, pxy, offs, feat_t, S);
    // out = S @ W_o^T + b_o : [7200 x 256]
    gemm_bf16<true, false><<<dim3(113, 4, 1), 256, 0, stream>>>(
        S, 0, W_o, b_o, d_out, 0, 7200, 256, 256, 256);
}

// Round 6
// 293.566 us; speedup vs baseline: 1.5166x; 1.5166x over previous
//
#include <hip/hip_runtime.h>

typedef __attribute__((ext_vector_type(4))) float f32x4;
typedef __attribute__((ext_vector_type(8))) short bf16x8;

__device__ __forceinline__ unsigned short f2bf(float f) {
    union { float f; unsigned int u; } x; x.f = f;
    unsigned int u = x.u;
    return (unsigned short)((u + 0x7FFFu + ((u >> 16) & 1u)) >> 16);
}
__device__ __forceinline__ float bf2f(unsigned short b) {
    union { unsigned int u; float f; } x; x.u = ((unsigned int)b) << 16;
    return x.f;
}

// blocked layout (row r, ch k), 128-row blocks: ((r>>7)*8 + (k>>5))*4096 + (r&127)*32 + (k&31)

// ---------------- prep: concat W_k|W_v (bf16, blocked) and biases ----------------
__global__ void prep_wkv(const float* __restrict__ Wk, const float* __restrict__ bk,
                         const float* __restrict__ Wv, const float* __restrict__ bv,
                         unsigned short* __restrict__ Wkv, float* __restrict__ bkv) {
    int i = blockIdx.x * 256 + threadIdx.x;
    if (i < 512 * 256) {
        int n = i >> 8, k = i & 255;
        float v = (n < 256) ? Wk[i] : Wv[i - 65536];
        Wkv[((size_t)(n >> 7) * 8 + (k >> 5)) * 4096 + (n & 127) * 32 + (k & 31)] = f2bf(v);
    }
    if (i < 512) bkv[i] = (i < 256) ? bk[i] : bv[i - 256];
}

// ---------------- prep: W_off -> blocked bf16 (64-row single block) ----------------
__global__ void prep_woff(const float* __restrict__ Woff, unsigned short* __restrict__ Woffp) {
    int n = blockIdx.x, k = threadIdx.x;
    Woffp[(k >> 5) * 2048 + n * 32 + (k & 31)] = f2bf(Woff[n * 256 + k]);
}

// ---------------- transpose features [48][256][2816] -> bf16 blocked ----------------
__global__ __launch_bounds__(256) void transpose_feat(const float* __restrict__ src,
                                                      unsigned short* __restrict__ dst) {
    __shared__ float tile[32][33];
    int img = blockIdx.z;
    int p0 = blockIdx.x * 32;   // pixel
    int d0 = blockIdx.y * 32;   // channel
    int tx = threadIdx.x & 31, ty = threadIdx.x >> 5;
    const float* s = src + (size_t)img * 256 * 2816;
#pragma unroll
    for (int i = 0; i < 4; i++) tile[ty + 8 * i][tx] = s[(size_t)(d0 + ty + 8 * i) * 2816 + p0 + tx];
    __syncthreads();
    int m = img * 2816 + p0;
    unsigned short* o = dst + ((size_t)(m >> 7) * 8 + (d0 >> 5)) * 4096 + (m & 127) * 32;
#pragma unroll
    for (int i = 0; i < 4; i++) o[(ty + 8 * i) * 32 + tx] = f2bf(tile[tx][ty + 8 * i]);
}

// ---------------- generic blocked bf16 GEMM: C[135168][NBLK*BN] = A @ B^T (+bias) ----------------
// A blocked (128-row blocks), B blocked (BN-row blocks). M = 135168 (1056 m-blocks).
template <int NBLK, int BN, bool BIAS, bool CBF16>
__global__ __launch_bounds__(256) void gemm_blk(
    const unsigned short* __restrict__ A,
    const unsigned short* __restrict__ B,
    const float* __restrict__ bias,
    void* __restrict__ Cv) {
    constexpr int WR = (BN == 128) ? 2 : 4;   // waves along M
    constexpr int FI = 128 / WR / 16;         // frag rows per wave
    constexpr int BPW = BN / 64;              // B stage chunks per wave
    constexpr int NTOT = NBLK * BN;

    __shared__ __align__(16) unsigned short Lds[4096 + BN * 32];
    unsigned short* Al = Lds;
    unsigned short* Bl = Lds + 4096;
    const int tid = threadIdx.x;
    const int lane = tid & 63, wave = tid >> 6;
    const int wr = wave % WR, wc = wave / WR;
    const int lrow = lane & 15, lk = lane >> 4;

    const int cpx = (1056 * NBLK) >> 3;       // blocks per XCD
    const int wgid = (blockIdx.x & 7) * cpx + (blockIdx.x >> 3);
    const int bm = wgid / NBLK, bn = wgid % NBLK;

    const unsigned short* Abase = A + (size_t)bm * 32768;
    const unsigned short* Bbase = B + (size_t)bn * (BN * 256);

    f32x4 acc[FI][4] = {};

    for (int kt = 0; kt < 8; ++kt) {
        if (kt) __syncthreads();
#pragma unroll
        for (int cc = 0; cc < 2; ++cc) {
            int ch = wave * 2 + cc;
            __builtin_amdgcn_global_load_lds(
                (const __attribute__((address_space(1))) unsigned int*)(Abase + kt * 4096 + ch * 512 + lane * 8),
                (__attribute__((address_space(3))) unsigned int*)&Al[ch * 512], 16, 0, 0);
        }
#pragma unroll
        for (int cc = 0; cc < BPW; ++cc) {
            int ch = wave * BPW + cc;
            __builtin_amdgcn_global_load_lds(
                (const __attribute__((address_space(1))) unsigned int*)(Bbase + kt * (BN * 32) + ch * 512 + lane * 8),
                (__attribute__((address_space(3))) unsigned int*)&Bl[ch * 512], 16, 0, 0);
        }
        __syncthreads();
        bf16x8 af[FI], bfr[4];
#pragma unroll
        for (int i = 0; i < FI; ++i)
            af[i] = *(const bf16x8*)&Al[(wr * (128 / WR) + i * 16 + lrow) * 32 + lk * 8];
#pragma unroll
        for (int j = 0; j < 4; ++j)
            bfr[j] = *(const bf16x8*)&Bl[(wc * 64 + j * 16 + lrow) * 32 + lk * 8];
#pragma unroll
        for (int i = 0; i < FI; ++i)
#pragma unroll
            for (int j = 0; j < 4; ++j)
                acc[i][j] = __builtin_amdgcn_mfma_f32_16x16x32_bf16(af[i], bfr[j], acc[i][j], 0, 0, 0);
    }

    const int m0 = bm * 128, n0 = bn * BN;
    if (CBF16) {
        // BN==128: acc -> LDS (64x128 bf16 per pass) -> coalesced 16B stores
        unsigned short* C = (unsigned short*)Cv;
#pragma unroll
        for (int p = 0; p < 2; ++p) {
            __syncthreads();
            if (wr == p) {
#pragma unroll
                for (int j = 0; j < 4; ++j) {
                    float bs = BIAS ? bias[n0 + wc * 64 + j * 16 + lrow] : 0.f;
#pragma unroll
                    for (int i = 0; i < FI; ++i)
#pragma unroll
                        for (int jj = 0; jj < 4; ++jj)
                            Lds[(i * 16 + lk * 4 + jj) * 128 + wc * 64 + j * 16 + lrow] =
                                f2bf(acc[i][j][jj] + bs);
                }
            }
            __syncthreads();
#pragma unroll
            for (int r = 0; r < 4; ++r) {
                int idx = r * 256 + tid;
                int row = idx >> 4, col8 = idx & 15;
                *(f32x4*)(C + (size_t)(m0 + p * 64 + row) * NTOT + n0 + col8 * 8) =
                    *(const f32x4*)&Lds[row * 128 + col8 * 8];
            }
        }
    } else {
        float* C = (float*)Cv;
#pragma unroll
        for (int i = 0; i < FI; ++i)
#pragma unroll
            for (int j = 0; j < 4; ++j)
#pragma unroll
                for (int jj = 0; jj < 4; ++jj) {
                    int m = m0 + wr * (128 / WR) + i * 16 + lk * 4 + jj;
                    int n = wc * 64 + j * 16 + lrow;
                    float v = acc[i][j][jj];
                    if (BIAS) v += bias[n0 + n];
                    C[(size_t)m * NTOT + n0 + n] = v;
                }
    }
}

// ---------------- sample_offs: project points, bilinear-blend Foff, add qWoff ----------------
// block = bk (384 threads = 6 cams x 64). offs[cid][64], pxy[cid][2].
__global__ __launch_bounds__(384) void sample_offs(
    const float* __restrict__ points, const float* __restrict__ camM,
    const float* __restrict__ camb, const float* __restrict__ Foff,
    const float* __restrict__ qWoff,
    float* __restrict__ offs, float* __restrict__ pxy) {
    int bk = blockIdx.x;
    int b = bk / 900;
    int cam = threadIdx.x >> 6, j = threadIdx.x & 63;
    int cid = cam * 7200 + bk;

    float p0 = points[(size_t)bk * 3 + 0];
    float p1 = points[(size_t)bk * 3 + 1];
    float p2 = points[(size_t)bk * 3 + 2];
    const float* M = camM + cam * 6;
    float s0 = M[0] * p0 + M[1] * p1 + M[2] * p2 + camb[cam * 2 + 0];
    float s1 = M[3] * p0 + M[4] * p1 + M[5] * p2 + camb[cam * 2 + 1];
    float px0 = (1.f / (1.f + expf(-s0))) * 32.f;
    float px1 = (1.f / (1.f + expf(-s1))) * 88.f;
    float gx = 2.f * px0 / 32.f - 1.f, gy = 2.f * px1 / 88.f - 1.f;
    float ix = (gx + 1.f) * 0.5f * 87.f;
    float iy = (gy + 1.f) * 0.5f * 31.f;
    float x0 = floorf(ix), y0 = floorf(iy), x1 = x0 + 1.f, y1 = y0 + 1.f;
    float wx1 = ix - x0, wx0 = x1 - ix, wy1 = iy - y0, wy0 = y1 - iy;
    float m00 = (x0 >= 0.f && x0 <= 87.f && y0 >= 0.f && y0 <= 31.f) ? 1.f : 0.f;
    float m01 = (x1 >= 0.f && x1 <= 87.f && y0 >= 0.f && y0 <= 31.f) ? 1.f : 0.f;
    float m10 = (x0 >= 0.f && x0 <= 87.f && y1 >= 0.f && y1 <= 31.f) ? 1.f : 0.f;
    float m11 = (x1 >= 0.f && x1 <= 87.f && y1 >= 0.f && y1 <= 31.f) ? 1.f : 0.f;
    float w00 = wx0 * wy0 * m00, w01 = wx1 * wy0 * m01, w10 = wx0 * wy1 * m10, w11 = wx1 * wy1 * m11;
    int xi0 = (int)fminf(fmaxf(x0, 0.f), 87.f);
    int xi1 = (int)fminf(fmaxf(x1, 0.f), 87.f);
    int yi0 = (int)fminf(fmaxf(y0, 0.f), 31.f);
    int yi1 = (int)fminf(fmaxf(y1, 0.f), 31.f);

    size_t base = (size_t)(cam * 8 + b) * 2816;
    const float* f00 = Foff + (base + yi0 * 88 + xi0) * 64;
    const float* f01 = Foff + (base + yi0 * 88 + xi1) * 64;
    const float* f10 = Foff + (base + yi1 * 88 + xi0) * 64;
    const float* f11 = Foff + (base + yi1 * 88 + xi1) * 64;

    float o = qWoff[(size_t)bk * 64 + j]
            + w00 * f00[j] + w01 * f01[j] + w10 * f10[j] + w11 * f11[j];
    offs[(size_t)cid * 64 + j] = o;
    if (j == 0) { pxy[cid * 2 + 0] = px0; pxy[cid * 2 + 1] = px1; }
}

// ---------------- split-bf16 MFMA GEMM (fp32 A/B in): C = A@B^T + bias ----------------
template <bool SPLIT, bool C_BF16>
__global__ __launch_bounds__(256) void gemm_bf16(
    const float* __restrict__ A, long long aBatch,
    const float* __restrict__ B, const float* __restrict__ bias,
    void* __restrict__ Cv, long long cBatch,
    int M, int N, int K, int lda) {
    __shared__ __align__(16) unsigned short Ah[64][40];
    __shared__ __align__(16) unsigned short Bh[64][40];
    __shared__ __align__(16) unsigned short Al[(SPLIT ? 64 : 1)][40];
    __shared__ __align__(16) unsigned short Bl[(SPLIT ? 64 : 1)][40];

    const int tid = threadIdx.x;
    const int m0 = blockIdx.x * 64, n0 = blockIdx.y * 64;
    const int batch = blockIdx.z;
    const float* Ab = A + (size_t)batch * aBatch;
    const int lane = tid & 63, wave = tid >> 6;
    const int wr = wave & 1, wc = wave >> 1;
    const int lrow = lane & 15, lk = lane >> 4;

    f32x4 acc[2][2] = {};

    for (int kt = 0; kt < K; kt += 32) {
        if (kt) __syncthreads();
        {
            int c4 = (tid & 7) * 4;
#pragma unroll
            for (int rep = 0; rep < 2; rep++) {
                int r = (tid >> 3) + rep * 32;
                int m = m0 + r; if (m >= M) m = M - 1;
                f32x4 v = *(const f32x4*)(Ab + (size_t)m * lda + kt + c4);
#pragma unroll
                for (int q = 0; q < 4; q++) {
                    unsigned short h = f2bf(v[q]);
                    Ah[r][c4 + q] = h;
                    if (SPLIT) Al[r][c4 + q] = f2bf(v[q] - bf2f(h));
                }
            }
        }
        {
            int c4 = (tid & 7) * 4;
#pragma unroll
            for (int rep = 0; rep < 2; rep++) {
                int r = (tid >> 3) + rep * 32;
                f32x4 v = *(const f32x4*)(B + (size_t)(n0 + r) * K + kt + c4);
#pragma unroll
                for (int q = 0; q < 4; q++) {
                    unsigned short h = f2bf(v[q]);
                    Bh[r][c4 + q] = h;
                    if (SPLIT) Bl[r][c4 + q] = f2bf(v[q] - bf2f(h));
                }
            }
        }
        __syncthreads();

        bf16x8 a_h[2], b_h[2], a_l[2], b_l[2];
#pragma unroll
        for (int i = 0; i < 2; i++) {
            a_h[i] = *(const bf16x8*)&Ah[wr * 32 + i * 16 + lrow][lk * 8];
            b_h[i] = *(const bf16x8*)&Bh[wc * 32 + i * 16 + lrow][lk * 8];
            if (SPLIT) {
                a_l[i] = *(const bf16x8*)&Al[wr * 32 + i * 16 + lrow][lk * 8];
                b_l[i] = *(const bf16x8*)&Bl[wc * 32 + i * 16 + lrow][lk * 8];
            }
        }
#pragma unroll
        for (int i = 0; i < 2; i++)
#pragma unroll
            for (int j = 0; j < 2; j++) {
                acc[i][j] = __builtin_amdgcn_mfma_f32_16x16x32_bf16(a_h[i], b_h[j], acc[i][j], 0, 0, 0);
                if (SPLIT) {
                    acc[i][j] = __builtin_amdgcn_mfma_f32_16x16x32_bf16(a_h[i], b_l[j], acc[i][j], 0, 0, 0);
                    acc[i][j] = __builtin_amdgcn_mfma_f32_16x16x32_bf16(a_l[i], b_h[j], acc[i][j], 0, 0, 0);
                }
            }
    }

#pragma unroll
    for (int i = 0; i < 2; i++)
#pragma unroll
        for (int j = 0; j < 2; j++) {
            int n = n0 + wc * 32 + j * 16 + lrow;
            float bs = bias[n];
#pragma unroll
            for (int jj = 0; jj < 4; jj++) {
                int m = m0 + wr * 32 + i * 16 + lk * 4 + jj;
                if (m < M) {
                    float val = acc[i][j][jj] + bs;
                    if (C_BF16)
                        ((unsigned short*)Cv)[(size_t)batch * cBatch + (size_t)m * N + n] = f2bf(val);
                    else
                        ((float*)Cv)[(size_t)batch * cBatch + (size_t)m * N + n] = val;
                }
            }
        }
}

// ---------------- fused deformable attention (kv_t based) ----------------
__global__ __launch_bounds__(512) void attn_kernel(
    const float* __restrict__ q_proj, const float* __restrict__ pxy,
    const float* __restrict__ offs, const unsigned short* __restrict__ kv_t,
    float* __restrict__ S) {
    int bk = blockIdx.x;            // b*900 + k
    int b = bk / 900, k = bk % 900;
    int h = threadIdx.x >> 6;       // wave = head
    int lane = threadIdx.x & 63;

    __shared__ __align__(16) float        ldsW[8][24][4];
    __shared__ __align__(16) unsigned int ldsI[8][24][4];
    __shared__ float ldsL[8][24];

    if (lane < 24) {
        int cam = lane >> 2, p = lane & 3;
        int cid = cam * 7200 + bk;
        float px0 = pxy[cid * 2 + 0], px1 = pxy[cid * 2 + 1];
        float o0 = offs[(size_t)cid * 64 + (h * 4 + p) * 2 + 0];
        float o1 = offs[(size_t)cid * 64 + (h * 4 + p) * 2 + 1];
        float pc0 = px0 + o0 * (1.f / 32.f);
        float pc1 = px1 + o1 * (1.f / 88.f);
        float gx = 2.f * (pc0 * (1.f / 32.f)) - 1.f;
        float gy = 2.f * (pc1 * (1.f / 88.f)) - 1.f;
        float ix = (gx + 1.f) * 0.5f * 87.f;
        float iy = (gy + 1.f) * 0.5f * 31.f;
        float x0 = floorf(ix), y0 = floorf(iy), x1 = x0 + 1.f, y1 = y0 + 1.f;
        float wx1 = ix - x0, wx0 = x1 - ix, wy1 = iy - y0, wy0 = y1 - iy;
        float m00 = (x0 >= 0.f && x0 <= 87.f && y0 >= 0.f && y0 <= 31.f) ? 1.f : 0.f;
        float m01 = (x1 >= 0.f && x1 <= 87.f && y0 >= 0.f && y0 <= 31.f) ? 1.f : 0.f;
        float m10 = (x0 >= 0.f && x0 <= 87.f && y1 >= 0.f && y1 <= 31.f) ? 1.f : 0.f;
        float m11 = (x1 >= 0.f && x1 <= 87.f && y1 >= 0.f && y1 <= 31.f) ? 1.f : 0.f;
        int xi0 = (int)fminf(fmaxf(x0, 0.f), 87.f);
        int xi1 = (int)fminf(fmaxf(x1, 0.f), 87.f);
        int yi0 = (int)fminf(fmaxf(y0, 0.f), 31.f);
        int yi1 = (int)fminf(fmaxf(y1, 0.f), 31.f);
        unsigned int img = (unsigned int)(cam * 8 + b) * 2816u;
        ldsW[h][lane][0] = wx0 * wy0 * m00;
        ldsW[h][lane][1] = wx1 * wy0 * m01;
        ldsW[h][lane][2] = wx0 * wy1 * m10;
        ldsW[h][lane][3] = wx1 * wy1 * m11;
        ldsI[h][lane][0] = (img + yi0 * 88 + xi0) * 1024u;
        ldsI[h][lane][1] = (img + yi0 * 88 + xi1) * 1024u;
        ldsI[h][lane][2] = (img + yi1 * 88 + xi0) * 1024u;
        ldsI[h][lane][3] = (img + yi1 * 88 + xi1) * 1024u;
    }
    __syncthreads();

    const int d2 = lane & 15;               // channel pair
    const int pt = lane >> 5;               // point parity in flight
    const int chB = (((lane >> 4) & 1) * 256 + h * 32 + d2 * 2) * 2;  // byte offset
    const char* kvb = (const char*)kv_t;

    float q0 = q_proj[(size_t)bk * 256 + h * 32 + d2 * 2];
    float q1 = q_proj[(size_t)bk * 256 + h * 32 + d2 * 2 + 1];

    float vr0[12], vr1[12];
    const float inv_sqrt = 0.17677669529663687f;
#pragma unroll
    for (int lp = 0; lp < 12; lp++) {
        int l = lp * 2 + pt;
        f32x4 w = *(const f32x4*)ldsW[h][l];
        unsigned int i0 = ldsI[h][l][0], i1 = ldsI[h][l][1];
        unsigned int i2 = ldsI[h][l][2], i3 = ldsI[h][l][3];
        unsigned int u0 = *(const unsigned int*)(kvb + i0 + chB);
        unsigned int u1 = *(const unsigned int*)(kvb + i1 + chB);
        unsigned int u2 = *(const unsigned int*)(kvb + i2 + chB);
        unsigned int u3 = *(const unsigned int*)(kvb + i3 + chB);
        float a0 = w[0] * bf2f((unsigned short)u0) + w[1] * bf2f((unsigned short)u1)
                 + w[2] * bf2f((unsigned short)u2) + w[3] * bf2f((unsigned short)u3);
        float a1 = w[0] * bf2f((unsigned short)(u0 >> 16)) + w[1] * bf2f((unsigned short)(u1 >> 16))
                 + w[2] * bf2f((unsigned short)(u2 >> 16)) + w[3] * bf2f((unsigned short)(u3 >> 16));
        float t = q0 * a0 + q1 * a1;
        t += __shfl_xor(t, 1);
        t += __shfl_xor(t, 2);
        t += __shfl_xor(t, 4);
        t += __shfl_xor(t, 8);
        if ((lane & 31) == 0) ldsL[h][l] = t * inv_sqrt;
        vr0[lp] = a0; vr1[lp] = a1;
    }
    __syncthreads();

    float mx = -1e30f;
#pragma unroll
    for (int l = 0; l < 24; l++) mx = fmaxf(mx, ldsL[h][l]);
    float ssum = 0.f;
    float at12[12];
#pragma unroll
    for (int l = 0; l < 24; l++) {
        float e = __expf(ldsL[h][l] - mx);
        ssum += e;
        if ((l & 1) == 0) { if (pt == 0) at12[l >> 1] = e; }
        else              { if (pt == 1) at12[l >> 1] = e; }
    }
    float inv = 1.f / ssum;
    float o0 = 0.f, o1 = 0.f;
#pragma unroll
    for (int lp = 0; lp < 12; lp++) {
        float a = at12[lp] * inv;
        o0 += a * vr0[lp];
        o1 += a * vr1[lp];
    }
    o0 += __shfl_xor(o0, 32);
    o1 += __shfl_xor(o1, 32);
    if ((lane >> 4) == 1) {   // lanes 16..31: v-lanes, pt 0
        float2 ov; ov.x = o0; ov.y = o1;
        *(float2*)&S[(size_t)b * 230400 + (size_t)h * 28800 + k * 32 + d2 * 2] = ov;
    }
}

extern "C" void kernel_launch(void* const* d_in, const int* in_sizes, int n_in,
                              void* d_out, int out_size, void* d_ws, size_t ws_size,
                              hipStream_t stream) {
    const float* query    = (const float*)d_in[0];
    const float* points   = (const float*)d_in[1];
    const float* features = (const float*)d_in[2];
    const float* camM     = (const float*)d_in[3];
    const float* camb     = (const float*)d_in[4];
    const float* W_off    = (const float*)d_in[5];
    const float* b_off    = (const float*)d_in[6];
    const float* W_q      = (const float*)d_in[7];
    const float* b_q      = (const float*)d_in[8];
    const float* W_k      = (const float*)d_in[9];
    const float* b_k      = (const float*)d_in[10];
    const float* W_v      = (const float*)d_in[11];
    const float* b_v      = (const float*)d_in[12];
    const float* W_o      = (const float*)d_in[13];
    const float* b_o      = (const float*)d_in[14];

    char* ws = (char*)d_ws;
    unsigned short* feat_t = (unsigned short*)ws; ws += 69206016;   // blocked [1056][8][128][32] bf16
    unsigned short* kv_t   = (unsigned short*)ws; ws += 138412032;  // [135168][512] bf16
    float* Foff   = (float*)ws; ws += 34603008;                     // [135168][64]
    float* offs   = (float*)ws; ws += 11059200;                     // [43200][64]
    float* pxy    = (float*)ws; ws += 345600;                       // [43200][2]
    float* qWoff  = (float*)ws; ws += 1843200;                      // [7200][64]
    float* q_proj = (float*)ws; ws += 7372800;                      // [7200][256]
    float* S      = (float*)ws; ws += 7372800;                      // [8][230400] scrambled
    unsigned short* Wkv = (unsigned short*)ws; ws += 524288;        // blocked [4][8][128][32] bf16
    float* bkv    = (float*)ws; ws += 2048;                         // [512]
    unsigned short* Woffp = (unsigned short*)ws; ws += 32768;       // blocked [8][64][32] bf16

    prep_wkv<<<512, 256, 0, stream>>>(W_k, b_k, W_v, b_v, Wkv, bkv);
    prep_woff<<<64, 256, 0, stream>>>(W_off, Woffp);
    transpose_feat<<<dim3(88, 8, 48), 256, 0, stream>>>(features, feat_t);
    // kv_t = feat_t @ Wkv^T + bkv : [135168 x 512] bf16
    gemm_blk<4, 128, true, true><<<4224, 256, 0, stream>>>(feat_t, Wkv, bkv, kv_t);
    // Foff = feat_t @ W_off^T : [135168 x 64] fp32 (no bias)
    gemm_blk<1, 64, false, false><<<1056, 256, 0, stream>>>(feat_t, Woffp, nullptr, Foff);
    // qWoff = query @ W_off^T + b_off : [7200 x 64]
    gemm_bf16<true, false><<<dim3(113, 1, 1), 256, 0, stream>>>(
        query, 0, W_off, b_off, qWoff, 0, 7200, 64, 256, 256);
    // offs[cid][64] = qWoff[bk] + bilinear(Foff); pxy
    sample_offs<<<7200, 384, 0, stream>>>(points, camM, camb, Foff, qWoff, offs, pxy);
    // q_proj = query @ W_q^T + b_q : [7200 x 256]
    gemm_bf16<true, false><<<dim3(113, 4, 1), 256, 0, stream>>>(
        query, 0, W_q, b_q, q_proj, 0, 7200, 256, 256, 256);
    attn_kernel<<<7200, 512, 0, stream>>>(q_proj, pxy, offs, kv_t, S);
    // out = S @ W_o^T + b_o : [7200 x 256]
    gemm_bf16<true, false><<<dim3(113, 4, 1), 256, 0, stream>>>(
        S, 0, W_o, b_o, d_out, 0, 7200, 256, 256, 256);
}